// Round 2
// baseline (78.515 us; speedup 1.0000x reference)
//
#include <hip/hip_runtime.h>
#include <math.h>

#define NSAMP 128
#define NEAR_T 0.1f
#define FAR_T  2.0f

__global__ __launch_bounds__(256) void nerf_march_kernel(
    const float* __restrict__ ro, const float* __restrict__ rd,
    const float* __restrict__ W1, const float* __restrict__ Wrgb,
    const float* __restrict__ Wd, float* __restrict__ out, int nrays)
{
    // Staged uniform weights: one ds_read_b128 per j, broadcast to all lanes.
    __shared__ float4 w1t[32];  // {W1[0][j], W1[1][j], W1[2][j], 0}
    __shared__ float4 wcd[32];  // {Wrgb[j][0], Wrgb[j][1], Wrgb[j][2], Wd[j]}

    const int tid = threadIdx.x;
    if (tid < 32) {
        const int j = tid;
        w1t[j] = make_float4(W1[j], W1[32 + j], W1[64 + j], 0.0f);
        wcd[j] = make_float4(Wrgb[j * 3 + 0], Wrgb[j * 3 + 1], Wrgb[j * 3 + 2], Wd[j]);
    }
    __syncthreads();

    const int wave = tid >> 6;
    const int lane = tid & 63;
    const int ray  = blockIdx.x * 4 + wave;
    if (ray >= nrays) return;

    const float ox = ro[ray * 3 + 0], oy = ro[ray * 3 + 1], oz = ro[ray * 3 + 2];
    const float dx = rd[ray * 3 + 0], dy = rd[ray * 3 + 1], dz = rd[ray * 3 + 2];

    // Per-ray hoist: h_j(t) = relu(a_j + t * b_j)
    float2 ab[32];
    #pragma unroll
    for (int j = 0; j < 32; ++j) {
        const float4 w = w1t[j];
        const float a = fmaf(ox, w.x, fmaf(oy, w.y, oz * w.z));
        const float b = fmaf(dx, w.x, fmaf(dy, w.y, dz * w.z));
        ab[j] = make_float2(a, b);
    }

    const float step = (FAR_T - NEAR_T) / (float)(NSAMP - 1);
    const float t0 = NEAR_T + (float)(2 * lane) * step;
    const float t1 = t0 + step;

    // Two samples per lane: accumulate density + 3 sigmoid pre-activations.
    float de0 = 0.f, de1 = 0.f;
    float sr0 = 0.f, sr1 = 0.f, sg0 = 0.f, sg1 = 0.f, sb0 = 0.f, sb1 = 0.f;
    #pragma unroll
    for (int j = 0; j < 32; ++j) {
        const float2 abj = ab[j];
        const float h0 = fmaxf(fmaf(t0, abj.y, abj.x), 0.f);
        const float h1 = fmaxf(fmaf(t1, abj.y, abj.x), 0.f);
        const float4 w = wcd[j];
        sr0 = fmaf(h0, w.x, sr0); sr1 = fmaf(h1, w.x, sr1);
        sg0 = fmaf(h0, w.y, sg0); sg1 = fmaf(h1, w.y, sg1);
        sb0 = fmaf(h0, w.z, sb0); sb1 = fmaf(h1, w.z, sb1);
        de0 = fmaf(h0, w.w, de0); de1 = fmaf(h1, w.w, de1);
    }
    de0 = fmaxf(de0, 0.f);
    de1 = fmaxf(de1, 0.f);

    // sigmoid(x) = 1 / (1 + exp(-x))
    const float cr0 = __fdividef(1.f, 1.f + __expf(-sr0));
    const float cr1 = __fdividef(1.f, 1.f + __expf(-sr1));
    const float cg0 = __fdividef(1.f, 1.f + __expf(-sg0));
    const float cg1 = __fdividef(1.f, 1.f + __expf(-sg1));
    const float cb0 = __fdividef(1.f, 1.f + __expf(-sb0));
    const float cb1 = __fdividef(1.f, 1.f + __expf(-sb1));

    // alpha / transmittance factors. Last sample (s=127, lane 63) has delta=1e10.
    const float del1 = (lane == 63) ? 1e10f : step;
    const float e0 = __expf(-de0 * step);
    const float e1 = __expf(-de1 * del1);
    const float alpha0 = 1.f - e0;
    const float alpha1 = 1.f - e1;
    const float q0 = e0 + 1e-10f;   // == (1 - alpha0 + 1e-10)
    const float q1 = e1 + 1e-10f;

    // Local (within-lane) weighted rgb, pending the cross-lane prefix product.
    const float w0 = alpha0;
    const float w1 = alpha1 * q0;
    float cr = w0 * cr0 + w1 * cr1;
    float cg = w0 * cg0 + w1 * cg1;
    float cb = w0 * cb0 + w1 * cb1;
    const float p = q0 * q1;

    // Inclusive prefix product over lanes, then exclusive shift.
    float incl = p;
    #pragma unroll
    for (int ofs = 1; ofs < 64; ofs <<= 1) {
        const float v = __shfl_up(incl, ofs, 64);
        if (lane >= ofs) incl *= v;
    }
    float excl = __shfl_up(incl, 1, 64);
    if (lane == 0) excl = 1.f;

    cr *= excl; cg *= excl; cb *= excl;

    // Wave-wide sum of the 3 components.
    #pragma unroll
    for (int m = 32; m > 0; m >>= 1) {
        cr += __shfl_down(cr, m, 64);
        cg += __shfl_down(cg, m, 64);
        cb += __shfl_down(cb, m, 64);
    }

    if (lane == 0) {
        out[ray * 3 + 0] = cr;
        out[ray * 3 + 1] = cg;
        out[ray * 3 + 2] = cb;
    }
}

extern "C" void kernel_launch(void* const* d_in, const int* in_sizes, int n_in,
                              void* d_out, int out_size, void* d_ws, size_t ws_size,
                              hipStream_t stream) {
    const float* ro   = (const float*)d_in[0];
    const float* rd   = (const float*)d_in[1];
    const float* W1   = (const float*)d_in[2];
    const float* Wrgb = (const float*)d_in[3];
    const float* Wd   = (const float*)d_in[4];
    float* out = (float*)d_out;

    const int nrays = in_sizes[0] / 3;          // 4 * 4096 = 16384
    const int blocks = (nrays + 3) / 4;         // 4 rays (waves) per 256-thread block

    hipLaunchKernelGGL(nerf_march_kernel, dim3(blocks), dim3(256), 0, stream,
                       ro, rd, W1, Wrgb, Wd, out, nrays);
}

// Round 5
// 73.127 us; speedup vs baseline: 1.0737x; 1.0737x over previous
//
#include <hip/hip_runtime.h>
#include <math.h>

#define NSAMP 128
#define NEAR_T 0.1f
#define FAR_T  2.0f

__global__ __launch_bounds__(256) void nerf_march_kernel(
    const float* __restrict__ ro, const float* __restrict__ rd,
    const float* __restrict__ W1, const float* __restrict__ Wrgb,
    const float* __restrict__ Wd, float* __restrict__ out, int nrays)
{
    __shared__ float4 wcd[32];        // {Wrgb[j][0], Wrgb[j][1], Wrgb[j][2], Wd[j]}
    __shared__ float2 ablds[4][32];   // per-wave {a_j, b_j}

    const int tid  = threadIdx.x;
    const int wave = tid >> 6;
    const int lane = tid & 63;
    const int ray  = blockIdx.x * 4 + wave;
    const int rayc = (ray < nrays) ? ray : (nrays - 1);   // barrier-safe clamp

    if (tid < 32) {
        wcd[tid] = make_float4(Wrgb[tid * 3 + 0], Wrgb[tid * 3 + 1],
                               Wrgb[tid * 3 + 2], Wd[tid]);
    }

    // Distributed per-ray hoist: h_j(t) = relu(a_j + t*b_j).
    // Lane j (0..31) computes a_j = o·W1_j ; lane 32+j computes b_j = d·W1_j.
    {
        const int j = lane & 31;
        const float w0 = W1[j], w1 = W1[32 + j], w2 = W1[64 + j];
        const float* src = (lane < 32) ? ro : rd;
        const float x = src[rayc * 3 + 0];
        const float y = src[rayc * 3 + 1];
        const float z = src[rayc * 3 + 2];
        ((float*)&ablds[wave][j])[lane >> 5] = fmaf(x, w0, fmaf(y, w1, z * w2));
    }
    __syncthreads();

    const float step = (FAR_T - NEAR_T) / (float)(NSAMP - 1);
    const float t0 = NEAR_T + (float)(2 * lane) * step;
    const float t1 = t0 + step;

    // Two samples per lane: accumulate density + 3 sigmoid pre-activations.
    float de0 = 0.f, de1 = 0.f;
    float sr0 = 0.f, sr1 = 0.f, sg0 = 0.f, sg1 = 0.f, sb0 = 0.f, sb1 = 0.f;

    const float4* abp = (const float4*)&ablds[wave][0];
    #pragma unroll
    for (int jj = 0; jj < 16; ++jj) {
        const float4 ab = abp[jj];            // {a_{2jj}, b_{2jj}, a_{2jj+1}, b_{2jj+1}}
        const float4 wA = wcd[2 * jj + 0];
        const float4 wB = wcd[2 * jj + 1];
        {
            const float h0 = fmaxf(fmaf(t0, ab.y, ab.x), 0.f);
            const float h1 = fmaxf(fmaf(t1, ab.y, ab.x), 0.f);
            sr0 = fmaf(h0, wA.x, sr0); sr1 = fmaf(h1, wA.x, sr1);
            sg0 = fmaf(h0, wA.y, sg0); sg1 = fmaf(h1, wA.y, sg1);
            sb0 = fmaf(h0, wA.z, sb0); sb1 = fmaf(h1, wA.z, sb1);
            de0 = fmaf(h0, wA.w, de0); de1 = fmaf(h1, wA.w, de1);
        }
        {
            const float h0 = fmaxf(fmaf(t0, ab.w, ab.z), 0.f);
            const float h1 = fmaxf(fmaf(t1, ab.w, ab.z), 0.f);
            sr0 = fmaf(h0, wB.x, sr0); sr1 = fmaf(h1, wB.x, sr1);
            sg0 = fmaf(h0, wB.y, sg0); sg1 = fmaf(h1, wB.y, sg1);
            sb0 = fmaf(h0, wB.z, sb0); sb1 = fmaf(h1, wB.z, sb1);
            de0 = fmaf(h0, wB.w, de0); de1 = fmaf(h1, wB.w, de1);
        }
    }
    de0 = fmaxf(de0, 0.f);
    de1 = fmaxf(de1, 0.f);

    // sigmoid(x) = 1 / (1 + exp(-x))
    const float cr0 = __fdividef(1.f, 1.f + __expf(-sr0));
    const float cr1 = __fdividef(1.f, 1.f + __expf(-sr1));
    const float cg0 = __fdividef(1.f, 1.f + __expf(-sg0));
    const float cg1 = __fdividef(1.f, 1.f + __expf(-sg1));
    const float cb0 = __fdividef(1.f, 1.f + __expf(-sb0));
    const float cb1 = __fdividef(1.f, 1.f + __expf(-sb1));

    // alpha / transmittance factors. Last sample (s=127, lane 63) has delta=1e10.
    const float del1 = (lane == 63) ? 1e10f : step;
    const float e0 = __expf(-de0 * step);
    const float e1 = __expf(-de1 * del1);
    const float alpha0 = 1.f - e0;
    const float alpha1 = 1.f - e1;
    const float q0 = e0 + 1e-10f;   // == (1 - alpha0 + 1e-10)
    const float q1 = e1 + 1e-10f;

    // Local (within-lane) weighted rgb, pending the cross-lane prefix product.
    const float w0 = alpha0;
    const float w1 = alpha1 * q0;
    float cr = w0 * cr0 + w1 * cr1;
    float cg = w0 * cg0 + w1 * cg1;
    float cb = w0 * cb0 + w1 * cb1;
    const float p = q0 * q1;

    // Inclusive prefix product over lanes, then exclusive shift.
    float incl = p;
    #pragma unroll
    for (int ofs = 1; ofs < 64; ofs <<= 1) {
        const float v = __shfl_up(incl, ofs, 64);
        if (lane >= ofs) incl *= v;
    }
    float excl = __shfl_up(incl, 1, 64);
    if (lane == 0) excl = 1.f;

    cr *= excl; cg *= excl; cb *= excl;

    // Wave-wide sum of the 3 components.
    #pragma unroll
    for (int m = 32; m > 0; m >>= 1) {
        cr += __shfl_down(cr, m, 64);
        cg += __shfl_down(cg, m, 64);
        cb += __shfl_down(cb, m, 64);
    }

    if (lane == 0 && ray < nrays) {
        out[ray * 3 + 0] = cr;
        out[ray * 3 + 1] = cg;
        out[ray * 3 + 2] = cb;
    }
}

extern "C" void kernel_launch(void* const* d_in, const int* in_sizes, int n_in,
                              void* d_out, int out_size, void* d_ws, size_t ws_size,
                              hipStream_t stream) {
    const float* ro   = (const float*)d_in[0];
    const float* rd   = (const float*)d_in[1];
    const float* W1   = (const float*)d_in[2];
    const float* Wrgb = (const float*)d_in[3];
    const float* Wd   = (const float*)d_in[4];
    float* out = (float*)d_out;

    const int nrays = in_sizes[0] / 3;          // 4 * 4096 = 16384
    const int blocks = (nrays + 3) / 4;         // 4 rays (waves) per 256-thread block

    hipLaunchKernelGGL(nerf_march_kernel, dim3(blocks), dim3(256), 0, stream,
                       ro, rd, W1, Wrgb, Wd, out, nrays);
}